// Round 2
// baseline (119.293 us; speedup 1.0000x reference)
//
#include <hip/hip_runtime.h>

#define B_  16
#define LQ  256
#define LK  256
#define QD  256
#define HD  128
#define VD  128

// 2*log2(e): exp2(SCALE2*x) = e^{2x}
#define SCALE2 2.8853900817779268f
#define L2E    1.4426950408889634f
#define CTX_SIZE (B_ * LK * VD)

typedef float v2f __attribute__((ext_vector_type(2)));

__device__ __forceinline__ float fast_exp2(float x) { return __builtin_amdgcn_exp2f(x); }
__device__ __forceinline__ float fast_rcp(float x)  { return __builtin_amdgcn_rcpf(x); }

// ---------------------------------------------------------------------------
// proj_kernel: 1024 blocks x 256 threads (unchanged — known-good).
//   blocks [0,512):   qe_t[b][h][q] = exp2(SCALE2 * (query @ Wq))   (transposed)
//   blocks [512,1024): ke[b][k][h]  = exp2(SCALE2 * (key @ Wk))
// ---------------------------------------------------------------------------
__global__ __launch_bounds__(256) void proj_kernel(const float* __restrict__ query,
                                                   const float* __restrict__ key,
                                                   const float* __restrict__ Wq,
                                                   const float* __restrict__ Wk,
                                                   float* __restrict__ qe_t,
                                                   float* __restrict__ ke)
{
    __shared__ float  Xs[8][260];        // 8 rows x full K (=256), padded
    __shared__ float4 part[4][8][32];    // [wave][m][h-group] partial sums

    const int t = threadIdx.x;
    const bool isQ = (blockIdx.x < 512);
    const int blk  = isQ ? blockIdx.x : (blockIdx.x - 512);
    const int rows0 = blk * 8;
    const float* X = isQ ? query : key;
    const float* W = isQ ? Wq : Wk;

    // ---- stage X tile: 8 rows x 256 k (8 KB) ----
    {
        const int r = t >> 5;            // 0..7
        const int c = (t & 31) * 8;      // 0..248
        const float4 x0 = *(const float4*)(X + (size_t)(rows0 + r) * QD + c);
        const float4 x1 = *(const float4*)(X + (size_t)(rows0 + r) * QD + c + 4);
        *(float4*)&Xs[r][c]     = x0;
        *(float4*)&Xs[r][c + 4] = x1;
    }
    __syncthreads();

    const int w    = t >> 6;
    const int lane = t & 63;
    const int hg   = lane & 31;          // h4 = hg*4
    const int mb   = lane >> 5;          // 0/1; lane covers m = mb, mb+2, mb+4, mb+6

    float4 acc[4];
#pragma unroll
    for (int i = 0; i < 4; i++) acc[i] = make_float4(0.f, 0.f, 0.f, 0.f);

    const int kbase = w * 64;
#pragma unroll 4
    for (int kk = 0; kk < 64; kk++) {
        const int k = kbase + kk;
        const float4 wv = *(const float4*)(W + (size_t)k * HD + hg * 4);
#pragma unroll
        for (int mi = 0; mi < 4; mi++) {
            const float xv = Xs[mb + mi * 2][k];
            acc[mi].x += xv * wv.x;
            acc[mi].y += xv * wv.y;
            acc[mi].z += xv * wv.z;
            acc[mi].w += xv * wv.w;
        }
    }
#pragma unroll
    for (int mi = 0; mi < 4; mi++) part[w][mb + mi * 2][hg] = acc[mi];
    __syncthreads();

    // ---- reduce 4 partials, exp, store ----
    {
        const int m   = t >> 5;          // 0..7
        const int hg2 = t & 31;          // 0..31
        float4 s = part[0][m][hg2];
        const float4 p1 = part[1][m][hg2];
        const float4 p2 = part[2][m][hg2];
        const float4 p3 = part[3][m][hg2];
        s.x += p1.x + p2.x + p3.x;
        s.y += p1.y + p2.y + p3.y;
        s.z += p1.z + p2.z + p3.z;
        s.w += p1.w + p2.w + p3.w;
        float4 e = make_float4(fast_exp2(s.x * SCALE2), fast_exp2(s.y * SCALE2),
                               fast_exp2(s.z * SCALE2), fast_exp2(s.w * SCALE2));
        const int row = rows0 + m;
        if (isQ) {
            const int b = row >> 8, q = row & 255;
            float* base = qe_t + ((size_t)b * HD + hg2 * 4) * LQ + q;
            base[0 * LQ] = e.x;
            base[1 * LQ] = e.y;
            base[2 * LQ] = e.z;
            base[3 * LQ] = e.w;
        } else {
            *(float4*)(ke + (size_t)row * HD + hg2 * 4) = e;
        }
    }
}

// ---------------------------------------------------------------------------
// attn_kernel v2: 512 blocks x 256 threads. Block = (b, 8 consecutive k).
//  - k-tile 8 (was 4): halves qe_t / value L2 re-reads, amortizes qv loads 2x.
//  - packed fp32 (v2f + elementwise_fma -> v_pk_fma_f32) in phases 1 and 3.
// Phase 1: thread = q: score[k][q] = sumv - 2*sum_h v[h]*rcp(1 + qe[h][q]*ke[k][h])
// Phase 2: wave w -> softmax over q for k = w, w+4; write attention + attn_T LDS
// Phase 3: wave w -> q-range [w*64,w*64+64), all 8 k; LDS partial reduce -> context
// ---------------------------------------------------------------------------
__global__ __launch_bounds__(256) void attn_kernel(const float* __restrict__ qe_t,
                                                   const float* __restrict__ ke,
                                                   const float* __restrict__ v,
                                                   const float* __restrict__ value,
                                                   float* __restrict__ out)
{
    __shared__ float  score_s[8][260];
    __shared__ float  attn_T[256][8];    // [q][k] -> 2x float4 row per q
    __shared__ float2 partc[4][8][64];   // [wave][k][vd-pair]

    const int t  = threadIdx.x;
    const int b  = blockIdx.x >> 5;
    const int k0 = (blockIdx.x & 31) << 3;

    const float* qeb = qe_t + (size_t)b * HD * LQ;        // [h][q], holds e^{2qp}
    const float* keb = ke + ((size_t)b * LK + k0) * HD;   // 8 rows, e^{2kp}

    // ---- Phase 1 ----
    v2f acc[8];
#pragma unroll
    for (int i = 0; i < 8; i++) acc[i] = (v2f)0.f;

    const int q = t;
#pragma unroll 2
    for (int h0 = 0; h0 < HD; h0 += 8) {
        float qv[8];
#pragma unroll
        for (int j = 0; j < 8; j++) qv[j] = qeb[(size_t)(h0 + j) * LQ + q];
#pragma unroll
        for (int jp = 0; jp < 4; jp++) {
            v2f q2; q2.x = qv[2 * jp]; q2.y = qv[2 * jp + 1];
            const v2f vh2 = *(const v2f*)(v + h0 + 2 * jp);          // uniform -> s_load
#pragma unroll
            for (int kk = 0; kk < 8; kk++) {
                const v2f ke2 = *(const v2f*)(keb + kk * HD + h0 + 2 * jp); // uniform
                v2f tt = __builtin_elementwise_fma(q2, ke2, (v2f)1.0f);
                v2f r; r.x = fast_rcp(tt.x); r.y = fast_rcp(tt.y);
                acc[kk] = __builtin_elementwise_fma(vh2, r, acc[kk]);
            }
        }
    }
    float sumv = 0.f;  // wave-uniform, scalar pipe
#pragma unroll
    for (int h = 0; h < HD; h++) sumv += v[h];

#pragma unroll
    for (int kk = 0; kk < 8; kk++)
        score_s[kk][q] = sumv - 2.f * (acc[kk].x + acc[kk].y);
    __syncthreads();

    // ---- Phase 2: softmax over q; wave w handles k = w and w+4 ----
    const int w = t >> 6, lane = t & 63;
#pragma unroll
    for (int kh = 0; kh < 2; kh++) {
        const int kk = w + kh * 4;
        float x0 = score_s[kk][lane];
        float x1 = score_s[kk][lane + 64];
        float x2 = score_s[kk][lane + 128];
        float x3 = score_s[kk][lane + 192];
        float m = fmaxf(fmaxf(x0, x1), fmaxf(x2, x3));
#pragma unroll
        for (int off = 32; off >= 1; off >>= 1) m = fmaxf(m, __shfl_xor(m, off));
        float e0 = fast_exp2((x0 - m) * L2E);
        float e1 = fast_exp2((x1 - m) * L2E);
        float e2 = fast_exp2((x2 - m) * L2E);
        float e3 = fast_exp2((x3 - m) * L2E);
        float s = e0 + e1 + e2 + e3;
#pragma unroll
        for (int off = 32; off >= 1; off >>= 1) s += __shfl_xor(s, off);
        const float rs = fast_rcp(s);
        e0 *= rs; e1 *= rs; e2 *= rs; e3 *= rs;
        attn_T[lane][kk]       = e0;
        attn_T[lane + 64][kk]  = e1;
        attn_T[lane + 128][kk] = e2;
        attn_T[lane + 192][kk] = e3;
        float* ao = out + CTX_SIZE + ((size_t)(b * LK + k0 + kk)) * LQ;
        ao[lane]       = e0;
        ao[lane + 64]  = e1;
        ao[lane + 128] = e2;
        ao[lane + 192] = e3;
    }
    __syncthreads();

    // ---- Phase 3: context. Wave w sums its q-range for all 8 k ----
    {
        const int vd2 = lane * 2;
        const float* valb = value + (size_t)b * LQ * VD;
        v2f c[8];
#pragma unroll
        for (int i = 0; i < 8; i++) c[i] = (v2f)0.f;
#pragma unroll 4
        for (int i = 0; i < 64; i++) {
            const int q2 = (w << 6) + i;
            const float4 a0 = *(const float4*)&attn_T[q2][0];   // uniform -> broadcast
            const float4 a1 = *(const float4*)&attn_T[q2][4];
            const v2f vv = *(const v2f*)(valb + (size_t)q2 * VD + vd2);
            c[0] = __builtin_elementwise_fma((v2f)(a0.x), vv, c[0]);
            c[1] = __builtin_elementwise_fma((v2f)(a0.y), vv, c[1]);
            c[2] = __builtin_elementwise_fma((v2f)(a0.z), vv, c[2]);
            c[3] = __builtin_elementwise_fma((v2f)(a0.w), vv, c[3]);
            c[4] = __builtin_elementwise_fma((v2f)(a1.x), vv, c[4]);
            c[5] = __builtin_elementwise_fma((v2f)(a1.y), vv, c[5]);
            c[6] = __builtin_elementwise_fma((v2f)(a1.z), vv, c[6]);
            c[7] = __builtin_elementwise_fma((v2f)(a1.w), vv, c[7]);
        }
#pragma unroll
        for (int i = 0; i < 8; i++) partc[w][i][lane] = *(const float2*)&c[i];
    }
    __syncthreads();
    {
#pragma unroll
        for (int s0 = 0; s0 < 2; s0++) {
            const int si = t + s0 * 256;          // 512 outputs over 256 threads
            const int kg = si >> 6, l2 = si & 63;
            const float2 p0 = partc[0][kg][l2];
            const float2 p1 = partc[1][kg][l2];
            const float2 p2 = partc[2][kg][l2];
            const float2 p3 = partc[3][kg][l2];
            float2 r;
            r.x = p0.x + p1.x + p2.x + p3.x;
            r.y = p0.y + p1.y + p2.y + p3.y;
            *(float2*)(out + ((size_t)(b * LK + k0 + kg)) * VD + l2 * 2) = r;
        }
    }
}

extern "C" void kernel_launch(void* const* d_in, const int* in_sizes, int n_in,
                              void* d_out, int out_size, void* d_ws, size_t ws_size,
                              hipStream_t stream)
{
    const float* query = (const float*)d_in[0];
    const float* key   = (const float*)d_in[1];
    const float* value = (const float*)d_in[2];
    const float* Wq    = (const float*)d_in[3];
    const float* Wk    = (const float*)d_in[4];
    const float* v     = (const float*)d_in[5];
    float* out = (float*)d_out;

    float* qe_t = (float*)d_ws;                      // [B][HD][LQ], e^{2qp}
    float* kew  = qe_t + (size_t)B_ * HD * LQ;       // [B][LK][HD], e^{2kp}

    proj_kernel<<<dim3(1024), 256, 0, stream>>>(query, key, Wq, Wk, qe_t, kew);
    attn_kernel<<<dim3(512), 256, 0, stream>>>(qe_t, kew, v, value, out);
}

// Round 3
// 104.483 us; speedup vs baseline: 1.1417x; 1.1417x over previous
//
#include <hip/hip_runtime.h>

#define B_  16
#define LQ  256
#define LK  256
#define QD  256
#define HD  128
#define VD  128

// 2*log2(e): exp2(SCALE2*x) = e^{2x}
#define SCALE2 2.8853900817779268f
#define L2E    1.4426950408889634f
#define CTX_SIZE (B_ * LK * VD)

typedef float v2f __attribute__((ext_vector_type(2)));

__device__ __forceinline__ float fast_exp2(float x) { return __builtin_amdgcn_exp2f(x); }
__device__ __forceinline__ float fast_rcp(float x)  { return __builtin_amdgcn_rcpf(x); }

// ---------------------------------------------------------------------------
// proj_kernel: 1024 blocks x 256 threads (unchanged — known-good).
//   blocks [0,512):   qe_t[b][h][q] = exp2(SCALE2 * (query @ Wq))   (transposed)
//   blocks [512,1024): ke[b][k][h]  = exp2(SCALE2 * (key @ Wk))
// ---------------------------------------------------------------------------
__global__ __launch_bounds__(256) void proj_kernel(const float* __restrict__ query,
                                                   const float* __restrict__ key,
                                                   const float* __restrict__ Wq,
                                                   const float* __restrict__ Wk,
                                                   float* __restrict__ qe_t,
                                                   float* __restrict__ ke)
{
    __shared__ float  Xs[8][260];        // 8 rows x full K (=256), padded
    __shared__ float4 part[4][8][32];    // [wave][m][h-group] partial sums

    const int t = threadIdx.x;
    const bool isQ = (blockIdx.x < 512);
    const int blk  = isQ ? blockIdx.x : (blockIdx.x - 512);
    const int rows0 = blk * 8;
    const float* X = isQ ? query : key;
    const float* W = isQ ? Wq : Wk;

    // ---- stage X tile: 8 rows x 256 k (8 KB) ----
    {
        const int r = t >> 5;            // 0..7
        const int c = (t & 31) * 8;      // 0..248
        const float4 x0 = *(const float4*)(X + (size_t)(rows0 + r) * QD + c);
        const float4 x1 = *(const float4*)(X + (size_t)(rows0 + r) * QD + c + 4);
        *(float4*)&Xs[r][c]     = x0;
        *(float4*)&Xs[r][c + 4] = x1;
    }
    __syncthreads();

    const int w    = t >> 6;
    const int lane = t & 63;
    const int hg   = lane & 31;          // h4 = hg*4
    const int mb   = lane >> 5;          // 0/1; lane covers m = mb, mb+2, mb+4, mb+6

    float4 acc[4];
#pragma unroll
    for (int i = 0; i < 4; i++) acc[i] = make_float4(0.f, 0.f, 0.f, 0.f);

    const int kbase = w * 64;
#pragma unroll 4
    for (int kk = 0; kk < 64; kk++) {
        const int k = kbase + kk;
        const float4 wv = *(const float4*)(W + (size_t)k * HD + hg * 4);
#pragma unroll
        for (int mi = 0; mi < 4; mi++) {
            const float xv = Xs[mb + mi * 2][k];
            acc[mi].x += xv * wv.x;
            acc[mi].y += xv * wv.y;
            acc[mi].z += xv * wv.z;
            acc[mi].w += xv * wv.w;
        }
    }
#pragma unroll
    for (int mi = 0; mi < 4; mi++) part[w][mb + mi * 2][hg] = acc[mi];
    __syncthreads();

    // ---- reduce 4 partials, exp, store ----
    {
        const int m   = t >> 5;          // 0..7
        const int hg2 = t & 31;          // 0..31
        float4 s = part[0][m][hg2];
        const float4 p1 = part[1][m][hg2];
        const float4 p2 = part[2][m][hg2];
        const float4 p3 = part[3][m][hg2];
        s.x += p1.x + p2.x + p3.x;
        s.y += p1.y + p2.y + p3.y;
        s.z += p1.z + p2.z + p3.z;
        s.w += p1.w + p2.w + p3.w;
        float4 e = make_float4(fast_exp2(s.x * SCALE2), fast_exp2(s.y * SCALE2),
                               fast_exp2(s.z * SCALE2), fast_exp2(s.w * SCALE2));
        const int row = rows0 + m;
        if (isQ) {
            const int b = row >> 8, q = row & 255;
            float* base = qe_t + ((size_t)b * HD + hg2 * 4) * LQ + q;
            base[0 * LQ] = e.x;
            base[1 * LQ] = e.y;
            base[2 * LQ] = e.z;
            base[3 * LQ] = e.w;
        } else {
            *(float4*)(ke + (size_t)row * HD + hg2 * 4) = e;
        }
    }
}

// ---------------------------------------------------------------------------
// attn_kernel v3: 1024 blocks x 256 threads. Block = (b, 4 consecutive k).
//  - k-tile back to 4 (v1's occupancy: 4 waves/SIMD — v2's k-tile 8 halved
//    the grid and went latency-bound: VALUBusy 41%, occupancy 18.6%).
//  - KEEPS v2's packed fp32 math (v_pk_fma_f32) in phases 1 and 3.
// Phase 1: thread = q: score[k][q] = sumv - 2*sum_h v[h]*rcp(1 + qe[h][q]*ke[k][h])
// Phase 2: wave w -> softmax over q for k=w; write attention + attn_T LDS
// Phase 3: wave w -> q-range [w*64,w*64+64), all 4 k; LDS partial reduce -> context
// ---------------------------------------------------------------------------
__global__ __launch_bounds__(256) void attn_kernel(const float* __restrict__ qe_t,
                                                   const float* __restrict__ ke,
                                                   const float* __restrict__ v,
                                                   const float* __restrict__ value,
                                                   float* __restrict__ out)
{
    __shared__ float  score_s[4][260];
    __shared__ float  attn_T[256][4];    // [q][k] -> float4 row per q
    __shared__ float2 partc[4][4][64];   // [wave][k][vd-pair]

    const int t  = threadIdx.x;
    const int b  = blockIdx.x >> 6;
    const int k0 = (blockIdx.x & 63) << 2;

    const float* qeb = qe_t + (size_t)b * HD * LQ;        // [h][q], holds e^{2qp}
    const float* keb = ke + ((size_t)b * LK + k0) * HD;   // 4 rows, e^{2kp}

    // ---- Phase 1 ----
    v2f acc[4];
#pragma unroll
    for (int i = 0; i < 4; i++) acc[i] = (v2f)0.f;

    const int q = t;
#pragma unroll 2
    for (int h0 = 0; h0 < HD; h0 += 8) {
        float qv[8];
#pragma unroll
        for (int j = 0; j < 8; j++) qv[j] = qeb[(size_t)(h0 + j) * LQ + q];
#pragma unroll
        for (int jp = 0; jp < 4; jp++) {
            v2f q2; q2.x = qv[2 * jp]; q2.y = qv[2 * jp + 1];
            const v2f vh2 = *(const v2f*)(v + h0 + 2 * jp);          // uniform -> s_load
#pragma unroll
            for (int kk = 0; kk < 4; kk++) {
                const v2f ke2 = *(const v2f*)(keb + kk * HD + h0 + 2 * jp); // uniform
                v2f tt = __builtin_elementwise_fma(q2, ke2, (v2f)1.0f);
                v2f r; r.x = fast_rcp(tt.x); r.y = fast_rcp(tt.y);
                acc[kk] = __builtin_elementwise_fma(vh2, r, acc[kk]);
            }
        }
    }
    float sumv = 0.f;  // wave-uniform, scalar pipe
#pragma unroll
    for (int h = 0; h < HD; h++) sumv += v[h];

#pragma unroll
    for (int kk = 0; kk < 4; kk++)
        score_s[kk][q] = sumv - 2.f * (acc[kk].x + acc[kk].y);
    __syncthreads();

    // ---- Phase 2: softmax over q, wave w handles k=w ----
    const int w = t >> 6, lane = t & 63;
    {
        float x0 = score_s[w][lane];
        float x1 = score_s[w][lane + 64];
        float x2 = score_s[w][lane + 128];
        float x3 = score_s[w][lane + 192];
        float m = fmaxf(fmaxf(x0, x1), fmaxf(x2, x3));
#pragma unroll
        for (int off = 32; off >= 1; off >>= 1) m = fmaxf(m, __shfl_xor(m, off));
        float e0 = fast_exp2((x0 - m) * L2E);
        float e1 = fast_exp2((x1 - m) * L2E);
        float e2 = fast_exp2((x2 - m) * L2E);
        float e3 = fast_exp2((x3 - m) * L2E);
        float s = e0 + e1 + e2 + e3;
#pragma unroll
        for (int off = 32; off >= 1; off >>= 1) s += __shfl_xor(s, off);
        const float rs = fast_rcp(s);
        e0 *= rs; e1 *= rs; e2 *= rs; e3 *= rs;
        attn_T[lane][w]       = e0;
        attn_T[lane + 64][w]  = e1;
        attn_T[lane + 128][w] = e2;
        attn_T[lane + 192][w] = e3;
        float* ao = out + CTX_SIZE + ((size_t)(b * LK + k0 + w)) * LQ;
        ao[lane]       = e0;
        ao[lane + 64]  = e1;
        ao[lane + 128] = e2;
        ao[lane + 192] = e3;
    }
    __syncthreads();

    // ---- Phase 3: context. Wave w sums its q-range for all 4 k ----
    {
        const int vd2 = lane * 2;
        const float* valb = value + (size_t)b * LQ * VD;
        v2f c0 = (v2f)0.f, c1 = (v2f)0.f, c2 = (v2f)0.f, c3 = (v2f)0.f;
#pragma unroll 4
        for (int i = 0; i < 64; i++) {
            const int q2 = (w << 6) + i;
            const float4 a = *(const float4*)&attn_T[q2][0];    // uniform -> broadcast
            const v2f vv = *(const v2f*)(valb + (size_t)q2 * VD + vd2);
            c0 = __builtin_elementwise_fma((v2f)(a.x), vv, c0);
            c1 = __builtin_elementwise_fma((v2f)(a.y), vv, c1);
            c2 = __builtin_elementwise_fma((v2f)(a.z), vv, c2);
            c3 = __builtin_elementwise_fma((v2f)(a.w), vv, c3);
        }
        partc[w][0][lane] = *(const float2*)&c0;
        partc[w][1][lane] = *(const float2*)&c1;
        partc[w][2][lane] = *(const float2*)&c2;
        partc[w][3][lane] = *(const float2*)&c3;
    }
    __syncthreads();
    {
        const int kg = t >> 6, l2 = t & 63;
        const float2 p0 = partc[0][kg][l2];
        const float2 p1 = partc[1][kg][l2];
        const float2 p2 = partc[2][kg][l2];
        const float2 p3 = partc[3][kg][l2];
        float2 s;
        s.x = p0.x + p1.x + p2.x + p3.x;
        s.y = p0.y + p1.y + p2.y + p3.y;
        *(float2*)(out + ((size_t)(b * LK + k0 + kg)) * VD + l2 * 2) = s;
    }
}

extern "C" void kernel_launch(void* const* d_in, const int* in_sizes, int n_in,
                              void* d_out, int out_size, void* d_ws, size_t ws_size,
                              hipStream_t stream)
{
    const float* query = (const float*)d_in[0];
    const float* key   = (const float*)d_in[1];
    const float* value = (const float*)d_in[2];
    const float* Wq    = (const float*)d_in[3];
    const float* Wk    = (const float*)d_in[4];
    const float* v     = (const float*)d_in[5];
    float* out = (float*)d_out;

    float* qe_t = (float*)d_ws;                      // [B][HD][LQ], e^{2qp}
    float* kew  = qe_t + (size_t)B_ * HD * LQ;       // [B][LK][HD], e^{2kp}

    proj_kernel<<<dim3(1024), 256, 0, stream>>>(query, key, Wq, Wk, qe_t, kew);
    attn_kernel<<<dim3(1024), 256, 0, stream>>>(qe_t, kew, v, value, out);
}